// Round 4
// baseline (113.705 us; speedup 1.0000x reference)
//
#include <hip/hip_runtime.h>

#define DD 512
#define NNODE 96
#define NBATCH 4
#define MROWS (NBATCH * NNODE)   // 384
#define EPSF 1e-5f
#define INVN (1.0f / 96.0f)

// ---------------------------------------------------------------------------
// GEMM 1: a' = X @ Wa + b1  and  bb = X @ Wb   (X: 384x512, W: 512x512 in,out)
// grid (12, 32): blockIdx.y < 16 -> Wa (with bias) -> outA; else Wb -> outB.
// 64 threads (1 wave), 32x32 output tile, BK=16, prefetch-pipelined,
// LDS padded to 36 floats/row (keeps 16B alignment, kills bank conflicts).
// ---------------------------------------------------------------------------
__global__ __launch_bounds__(64) void gemm_ab(
    const float* __restrict__ X, const float* __restrict__ Wa,
    const float* __restrict__ Wb, const float* __restrict__ b1,
    float* __restrict__ outA, float* __restrict__ outB)
{
    __shared__ float Xs[16][36];   // [k][m]
    __shared__ float Ws[16][36];   // [k][n]
    const int tid = threadIdx.x;
    const int m0  = blockIdx.x * 32;
    const int nt  = blockIdx.y;
    const bool isA = nt < 16;
    const float* __restrict__ W = isA ? Wa : Wb;
    const int n0 = (nt & 15) * 32;

    const int xr = tid >> 1, xk = (tid & 1) * 8;     // X stage: row, k-offset
    const int wr = tid >> 2, wc = (tid & 3) * 8;     // W stage: k-row, col
    const int trow = (tid >> 3) * 4;                 // micro-tile row
    const int tcol = (tid & 7) * 4;                  // micro-tile col

    const float* xptr = X + (size_t)(m0 + xr) * DD + xk;
    const float* wptr = W + (size_t)wr * DD + n0 + wc;

    float4 xv0 = *(const float4*)(xptr);
    float4 xv1 = *(const float4*)(xptr + 4);
    float4 wv0 = *(const float4*)(wptr);
    float4 wv1 = *(const float4*)(wptr + 4);

    float acc[4][4] = {};

    for (int k0 = 0; k0 < DD; k0 += 16) {
        __syncthreads();
        Xs[xk + 0][xr] = xv0.x; Xs[xk + 1][xr] = xv0.y;
        Xs[xk + 2][xr] = xv0.z; Xs[xk + 3][xr] = xv0.w;
        Xs[xk + 4][xr] = xv1.x; Xs[xk + 5][xr] = xv1.y;
        Xs[xk + 6][xr] = xv1.z; Xs[xk + 7][xr] = xv1.w;
        *(float4*)&Ws[wr][wc]     = wv0;
        *(float4*)&Ws[wr][wc + 4] = wv1;
        __syncthreads();
        if (k0 + 16 < DD) {   // prefetch next K-slab; latency hides under FMAs
            xv0 = *(const float4*)(xptr + k0 + 16);
            xv1 = *(const float4*)(xptr + k0 + 20);
            wv0 = *(const float4*)(wptr + (size_t)(k0 + 16) * DD);
            wv1 = *(const float4*)(wptr + (size_t)(k0 + 16) * DD + 4);
        }
#pragma unroll
        for (int k = 0; k < 16; ++k) {
            const float4 a4 = *(const float4*)&Xs[k][trow];
            const float4 b4 = *(const float4*)&Ws[k][tcol];
            const float av[4] = {a4.x, a4.y, a4.z, a4.w};
            const float bv[4] = {b4.x, b4.y, b4.z, b4.w};
#pragma unroll
            for (int i = 0; i < 4; ++i)
#pragma unroll
                for (int j = 0; j < 4; ++j)
                    acc[i][j] = fmaf(av[i], bv[j], acc[i][j]);
        }
    }

    float bias[4] = {0.f, 0.f, 0.f, 0.f};
    if (isA) {
#pragma unroll
        for (int j = 0; j < 4; ++j) bias[j] = b1[n0 + tcol + j];
    }
    float* __restrict__ outp = isA ? outA : outB;
#pragma unroll
    for (int i = 0; i < 4; ++i) {
        float4 o;
        o.x = acc[i][0] + bias[0];
        o.y = acc[i][1] + bias[1];
        o.z = acc[i][2] + bias[2];
        o.w = acc[i][3] + bias[3];
        *(float4*)&outp[(size_t)(m0 + trow + i) * DD + n0 + tcol] = o;
    }
}

// ---------------------------------------------------------------------------
// relusum: s[b,i,d] = sum_j mask[b,i,j] * relu(a'[b,i,d] + bb[b,j,d])
//          cnt[b,i] = sum_j mask[b,i,j]        (computed once, by dz==0 WGs)
// grid (4, 24, 8), 64 threads. 4 i-rows per thread, mask rows in LDS
// (broadcast reads), bb streamed coalesced from L2.
// ---------------------------------------------------------------------------
__global__ __launch_bounds__(64) void relusum(
    const float* __restrict__ a, const float* __restrict__ bb,
    const float* __restrict__ mask, float* __restrict__ s,
    float* __restrict__ cnt)
{
    const int b  = blockIdx.x;
    const int i0 = blockIdx.y * 4;
    const int d  = blockIdx.z * 64 + threadIdx.x;
    const int tid = threadIdx.x;

    __shared__ float mk[4][96];
    for (int t = tid; t < 4 * 96; t += 64)
        mk[t / 96][t % 96] = mask[(size_t)(b * 96 + i0 + t / 96) * 96 + (t % 96)];
    __syncthreads();

    const float* arow = a + (size_t)(b * 96 + i0) * DD + d;
    const float a0 = arow[0], a1 = arow[DD], a2 = arow[2 * DD], a3 = arow[3 * DD];
    float s0 = 0.f, s1 = 0.f, s2 = 0.f, s3 = 0.f;

    const float* brow = bb + (size_t)b * 96 * DD + d;
#pragma unroll 4
    for (int j = 0; j < 96; ++j) {
        const float bv = brow[(size_t)j * DD];
        s0 = fmaf(mk[0][j], fmaxf(a0 + bv, 0.f), s0);
        s1 = fmaf(mk[1][j], fmaxf(a1 + bv, 0.f), s1);
        s2 = fmaf(mk[2][j], fmaxf(a2 + bv, 0.f), s2);
        s3 = fmaf(mk[3][j], fmaxf(a3 + bv, 0.f), s3);
    }

    float* srow = s + (size_t)(b * 96 + i0) * DD + d;
    srow[0] = s0; srow[DD] = s1; srow[2 * DD] = s2; srow[3 * DD] = s3;

    if (blockIdx.z == 0 && tid < 4) {
        float c = 0.f;
        for (int j = 0; j < 96; ++j) c += mk[tid][j];
        cnt[b * 96 + i0 + tid] = c;
    }
}

// ---------------------------------------------------------------------------
// GEMM 2 + residual: u[r,e] = hin[r,e] + INVN*( (S@W2)[r,e] + cnt[r]*b2[e] )
// grid (12, 16), 64 threads, same 32x32 tiled core as gemm_ab.
// ---------------------------------------------------------------------------
__global__ __launch_bounds__(64) void gemm_msg(
    const float* __restrict__ S, const float* __restrict__ W2,
    const float* __restrict__ b2, const float* __restrict__ cnt,
    const float* __restrict__ hin, float* __restrict__ U)
{
    __shared__ float Xs[16][36];
    __shared__ float Ws[16][36];
    const int tid = threadIdx.x;
    const int m0  = blockIdx.x * 32;
    const int n0  = blockIdx.y * 32;

    const int xr = tid >> 1, xk = (tid & 1) * 8;
    const int wr = tid >> 2, wc = (tid & 3) * 8;
    const int trow = (tid >> 3) * 4;
    const int tcol = (tid & 7) * 4;

    const float* xptr = S + (size_t)(m0 + xr) * DD + xk;
    const float* wptr = W2 + (size_t)wr * DD + n0 + wc;

    float4 xv0 = *(const float4*)(xptr);
    float4 xv1 = *(const float4*)(xptr + 4);
    float4 wv0 = *(const float4*)(wptr);
    float4 wv1 = *(const float4*)(wptr + 4);

    float acc[4][4] = {};

    for (int k0 = 0; k0 < DD; k0 += 16) {
        __syncthreads();
        Xs[xk + 0][xr] = xv0.x; Xs[xk + 1][xr] = xv0.y;
        Xs[xk + 2][xr] = xv0.z; Xs[xk + 3][xr] = xv0.w;
        Xs[xk + 4][xr] = xv1.x; Xs[xk + 5][xr] = xv1.y;
        Xs[xk + 6][xr] = xv1.z; Xs[xk + 7][xr] = xv1.w;
        *(float4*)&Ws[wr][wc]     = wv0;
        *(float4*)&Ws[wr][wc + 4] = wv1;
        __syncthreads();
        if (k0 + 16 < DD) {
            xv0 = *(const float4*)(xptr + k0 + 16);
            xv1 = *(const float4*)(xptr + k0 + 20);
            wv0 = *(const float4*)(wptr + (size_t)(k0 + 16) * DD);
            wv1 = *(const float4*)(wptr + (size_t)(k0 + 16) * DD + 4);
        }
#pragma unroll
        for (int k = 0; k < 16; ++k) {
            const float4 a4 = *(const float4*)&Xs[k][trow];
            const float4 b4 = *(const float4*)&Ws[k][tcol];
            const float av[4] = {a4.x, a4.y, a4.z, a4.w};
            const float bv[4] = {b4.x, b4.y, b4.z, b4.w};
#pragma unroll
            for (int i = 0; i < 4; ++i)
#pragma unroll
                for (int j = 0; j < 4; ++j)
                    acc[i][j] = fmaf(av[i], bv[j], acc[i][j]);
        }
    }

    float b2v[4];
#pragma unroll
    for (int j = 0; j < 4; ++j) b2v[j] = b2[n0 + tcol + j];

#pragma unroll
    for (int i = 0; i < 4; ++i) {
        const int r = m0 + trow + i;
        const float c = cnt[r] * INVN;
        const float4 h4 = *(const float4*)&hin[(size_t)r * DD + n0 + tcol];
        float4 o;
        o.x = h4.x + INVN * acc[i][0] + c * b2v[0];
        o.y = h4.y + INVN * acc[i][1] + c * b2v[1];
        o.z = h4.z + INVN * acc[i][2] + c * b2v[2];
        o.w = h4.w + INVN * acc[i][3] + c * b2v[3];
        *(float4*)&U[(size_t)r * DD + n0 + tcol] = o;
    }
}

// ---------------------------------------------------------------------------
// LayerNorm over last dim (512), biased variance, optional final clip.
// One WG (128 threads = 2 waves) per row; two-pass mean/var; butterfly
// __shfl_xor over 64 lanes + tiny LDS combine across the 2 waves.
// ---------------------------------------------------------------------------
__global__ __launch_bounds__(128) void layer_norm(
    const float* __restrict__ u, const float* __restrict__ gamma,
    const float* __restrict__ beta, float* __restrict__ out, int doClip)
{
    const int r   = blockIdx.x;
    const int tid = threadIdx.x;
    const float4 x = *(const float4*)&u[(size_t)r * DD + tid * 4];

    float s = x.x + x.y + x.z + x.w;
#pragma unroll
    for (int off = 32; off > 0; off >>= 1) s += __shfl_xor(s, off);

    __shared__ float red[2];
    __shared__ float red2[2];
    const int wid = tid >> 6;
    if ((tid & 63) == 0) red[wid] = s;
    __syncthreads();
    const float mu = (red[0] + red[1]) * (1.0f / 512.0f);

    const float dx = x.x - mu, dy = x.y - mu, dz = x.z - mu, dw = x.w - mu;
    float q = dx * dx + dy * dy + dz * dz + dw * dw;
#pragma unroll
    for (int off = 32; off > 0; off >>= 1) q += __shfl_xor(q, off);
    if ((tid & 63) == 0) red2[wid] = q;
    __syncthreads();
    const float var = (red2[0] + red2[1]) * (1.0f / 512.0f);
    const float rs  = rsqrtf(var + EPSF);

    const float4 g = *(const float4*)&gamma[tid * 4];
    const float4 bt = *(const float4*)&beta[tid * 4];
    float4 y;
    y.x = dx * rs * g.x + bt.x;
    y.y = dy * rs * g.y + bt.y;
    y.z = dz * rs * g.z + bt.z;
    y.w = dw * rs * g.w + bt.w;
    if (doClip) {
        y.x = fminf(fmaxf(y.x, -100.f), 100.f);
        y.y = fminf(fmaxf(y.y, -100.f), 100.f);
        y.z = fminf(fmaxf(y.z, -100.f), 100.f);
        y.w = fminf(fmaxf(y.w, -100.f), 100.f);
    }
    *(float4*)&out[(size_t)r * DD + tid * 4] = y;
}

// ---------------------------------------------------------------------------
extern "C" void kernel_launch(void* const* d_in, const int* in_sizes, int n_in,
                              void* d_out, int out_size, void* d_ws, size_t ws_size,
                              hipStream_t stream)
{
    const float* h0    = (const float*)d_in[0];  // (4,96,512)
    const float* adj   = (const float*)d_in[1];  // (4,96,96)
    const float* W1a   = (const float*)d_in[2];  // (2,512,512)
    const float* W1b   = (const float*)d_in[3];  // (2,512,512)
    const float* b1    = (const float*)d_in[4];  // (2,512)
    const float* W2    = (const float*)d_in[5];  // (2,512,512)
    const float* b2    = (const float*)d_in[6];  // (2,512)
    const float* gamma = (const float*)d_in[7];  // (512)
    const float* beta  = (const float*)d_in[8];  // (512)
    float* out = (float*)d_out;                  // (4,96,512)

    // workspace layout (floats): A | Bb | S | CNT | H1   (~3.15 MB total)
    float* ws  = (float*)d_ws;
    float* A   = ws;                       // 384*512   (a'; reused as U)
    float* Bb  = ws + 196608;              // 384*512
    float* S   = ws + 393216;              // 384*512
    float* CNT = ws + 589824;              // 384
    float* H1  = ws + 590208;              // 384*512

    for (int l = 0; l < 2; ++l) {
        const float* hin = (l == 0) ? h0 : H1;
        const float* w1a = W1a + (size_t)l * DD * DD;
        const float* w1b = W1b + (size_t)l * DD * DD;
        const float* bb1 = b1 + (size_t)l * DD;
        const float* w2  = W2 + (size_t)l * DD * DD;
        const float* bb2 = b2 + (size_t)l * DD;
        float* hout = (l == 0) ? H1 : out;

        gemm_ab<<<dim3(12, 32), 64, 0, stream>>>(hin, w1a, w1b, bb1, A, Bb);
        relusum<<<dim3(4, 24, 8), 64, 0, stream>>>(A, Bb, adj, S, CNT);
        gemm_msg<<<dim3(12, 16), 64, 0, stream>>>(S, w2, bb2, CNT, hin, A /*=U*/);
        layer_norm<<<dim3(384), 128, 0, stream>>>(A /*=U*/, gamma, beta, hout, l == 1);
    }
}

// Round 5
// 63.021 us; speedup vs baseline: 1.8042x; 1.8042x over previous
//
#include <hip/hip_runtime.h>

#define DD 512
#define NNODE 96
#define NBATCH 4
#define MROWS (NBATCH * NNODE)   // 384
#define EPSF 1e-5f
#define INVN (1.0f / 96.0f)

typedef short short8v __attribute__((ext_vector_type(8)));
typedef float f32x4   __attribute__((ext_vector_type(4)));

// round-to-nearest-even f32 -> bf16 (as raw ushort)
static __device__ __forceinline__ unsigned short f2bf(float x) {
    union { float f; unsigned int u; } v; v.f = x;
    unsigned int r = v.u + 0x7fffu + ((v.u >> 16) & 1u);
    return (unsigned short)(r >> 16);
}

// ---------------------------------------------------------------------------
// convert_w: z=0..5 -> transpose+convert weight matrix z (l=z/3, {W1a,W1b,W2})
//            into WT[z] as bf16 [n][k] (so MFMA B-fragments load 16B contig).
//            z=6 -> straight convert h0 (384x512) to bf16 row-major.
// grid (16,16,7), block (32,8). 33-padded LDS tile: conflict-free transpose.
// ---------------------------------------------------------------------------
__global__ __launch_bounds__(256) void convert_w(
    const float* __restrict__ W1a, const float* __restrict__ W1b,
    const float* __restrict__ W2, const float* __restrict__ h0,
    unsigned short* __restrict__ WT, unsigned short* __restrict__ Hbf)
{
    const int tx = threadIdx.x, ty = threadIdx.y;
    const int z = blockIdx.z;
    const int c0 = blockIdx.x * 32, r0 = blockIdx.y * 32;

    if (z == 6) {
        if (r0 >= MROWS) return;
#pragma unroll
        for (int i = 0; i < 4; ++i) {
            const int r = r0 + ty + 8 * i;
            Hbf[(size_t)r * DD + c0 + tx] = f2bf(h0[(size_t)r * DD + c0 + tx]);
        }
        return;
    }

    __shared__ float t[32][33];
    const int l = z / 3, w = z % 3;
    const float* __restrict__ src =
        (w == 0 ? W1a : (w == 1 ? W1b : W2)) + (size_t)l * DD * DD;
    unsigned short* __restrict__ dst = WT + (size_t)z * DD * DD;

#pragma unroll
    for (int i = 0; i < 4; ++i)
        t[ty + 8 * i][tx] = src[(size_t)(r0 + ty + 8 * i) * DD + c0 + tx];
    __syncthreads();
#pragma unroll
    for (int i = 0; i < 4; ++i)
        dst[(size_t)(c0 + ty + 8 * i) * DD + r0 + tx] = f2bf(t[tx][ty + 8 * i]);
}

// ---------------------------------------------------------------------------
// gemm_ab (MFMA): A' = Xbf @ Wa + b1 (fp32 out), Bb = Xbf @ Wb (fp32 out).
// One wave per 16x16 tile, K=512 -> 16 x mfma_f32_16x16x32_bf16.
// A frag: row = lane&15, k = 8*(lane>>4)+i (16B contig from row-major Xbf).
// B frag: col = lane&15, k = 8*(lane>>4)+i (16B contig from [n][k] WT).
// D: col = lane&15, row = 4*(lane>>4)+reg  [m89-verified layout].
// grid (6, 32, 2), block 256 (4 waves -> 4 consecutive m-tiles).
// ---------------------------------------------------------------------------
__global__ __launch_bounds__(256) void gemm_ab(
    const unsigned short* __restrict__ Xbf,
    const unsigned short* __restrict__ WaT,
    const unsigned short* __restrict__ WbT,
    const float* __restrict__ b1,
    float* __restrict__ outA, float* __restrict__ outB)
{
    const int lane = threadIdx.x & 63;
    const int wv   = threadIdx.x >> 6;
    const int m0   = (blockIdx.x * 4 + wv) * 16;
    const int n0   = blockIdx.y * 16;
    const int isB  = blockIdx.z;
    const unsigned short* __restrict__ Wt = isB ? WbT : WaT;

    const int lo = lane & 15, hi = lane >> 4;
    const unsigned short* ap = Xbf + (size_t)(m0 + lo) * DD + 8 * hi;
    const unsigned short* bp = Wt  + (size_t)(n0 + lo) * DD + 8 * hi;

    f32x4 acc = {0.f, 0.f, 0.f, 0.f};
#pragma unroll 4
    for (int k0 = 0; k0 < DD; k0 += 32) {
        const short8v a = *(const short8v*)(ap + k0);
        const short8v b = *(const short8v*)(bp + k0);
        acc = __builtin_amdgcn_mfma_f32_16x16x32_bf16(a, b, acc, 0, 0, 0);
    }

    const int col = n0 + lo;
    const float bias = isB ? 0.f : b1[col];
    float* __restrict__ outp = isB ? outB : outA;
    const int rb = m0 + 4 * hi;
#pragma unroll
    for (int i = 0; i < 4; ++i)
        outp[(size_t)(rb + i) * DD + col] = acc[i] + bias;
}

// ---------------------------------------------------------------------------
// relusum: s[b,i,d] = sum_j mask[b,i,j]*relu(a'[b,i,d] + bb[b,j,d]) -> bf16
//          cnt[b,i] = sum_j mask[b,i,j]
// grid (4, 24, 8), 64 threads. Mask rows in LDS (broadcast), bb from L2.
// ---------------------------------------------------------------------------
__global__ __launch_bounds__(64) void relusum(
    const float* __restrict__ a, const float* __restrict__ bb,
    const float* __restrict__ mask, unsigned short* __restrict__ s,
    float* __restrict__ cnt)
{
    const int b   = blockIdx.x;
    const int i0  = blockIdx.y * 4;
    const int d   = blockIdx.z * 64 + threadIdx.x;
    const int tid = threadIdx.x;

    __shared__ float mk[4][96];
    for (int t = tid; t < 4 * 96; t += 64)
        mk[t / 96][t % 96] = mask[(size_t)(b * 96 + i0 + t / 96) * 96 + (t % 96)];
    __syncthreads();

    const float* arow = a + (size_t)(b * 96 + i0) * DD + d;
    const float a0 = arow[0], a1 = arow[DD], a2 = arow[2 * DD], a3 = arow[3 * DD];
    float s0 = 0.f, s1 = 0.f, s2 = 0.f, s3 = 0.f;

    const float* brow = bb + (size_t)b * 96 * DD + d;
#pragma unroll 8
    for (int j = 0; j < 96; ++j) {
        const float bv = brow[(size_t)j * DD];
        s0 = fmaf(mk[0][j], fmaxf(a0 + bv, 0.f), s0);
        s1 = fmaf(mk[1][j], fmaxf(a1 + bv, 0.f), s1);
        s2 = fmaf(mk[2][j], fmaxf(a2 + bv, 0.f), s2);
        s3 = fmaf(mk[3][j], fmaxf(a3 + bv, 0.f), s3);
    }

    unsigned short* srow = s + (size_t)(b * 96 + i0) * DD + d;
    srow[0]      = f2bf(s0);
    srow[DD]     = f2bf(s1);
    srow[2 * DD] = f2bf(s2);
    srow[3 * DD] = f2bf(s3);

    if (blockIdx.z == 0 && tid < 4) {
        float c = 0.f;
        for (int j = 0; j < 96; ++j) c += mk[tid][j];
        cnt[b * 96 + i0 + tid] = c;
    }
}

// ---------------------------------------------------------------------------
// gemm_msg (MFMA) + residual: u = hin + INVN*(Sbf@W2 + cnt*b2)
// grid (6, 32), block 256. Same MFMA core; epilogue fuses residual + bias.
// ---------------------------------------------------------------------------
__global__ __launch_bounds__(256) void gemm_msg(
    const unsigned short* __restrict__ Sbf,
    const unsigned short* __restrict__ W2T,
    const float* __restrict__ b2, const float* __restrict__ cnt,
    const float* __restrict__ hin, float* __restrict__ U)
{
    const int lane = threadIdx.x & 63;
    const int wv   = threadIdx.x >> 6;
    const int m0   = (blockIdx.x * 4 + wv) * 16;
    const int n0   = blockIdx.y * 16;

    const int lo = lane & 15, hi = lane >> 4;
    const unsigned short* ap = Sbf + (size_t)(m0 + lo) * DD + 8 * hi;
    const unsigned short* bp = W2T + (size_t)(n0 + lo) * DD + 8 * hi;

    f32x4 acc = {0.f, 0.f, 0.f, 0.f};
#pragma unroll 4
    for (int k0 = 0; k0 < DD; k0 += 32) {
        const short8v a = *(const short8v*)(ap + k0);
        const short8v b = *(const short8v*)(bp + k0);
        acc = __builtin_amdgcn_mfma_f32_16x16x32_bf16(a, b, acc, 0, 0, 0);
    }

    const int col = n0 + lo;
    const float b2c = b2[col];
    const int rb = m0 + 4 * hi;
#pragma unroll
    for (int i = 0; i < 4; ++i) {
        const int r = rb + i;
        U[(size_t)r * DD + col] =
            hin[(size_t)r * DD + col] + INVN * acc[i] + (cnt[r] * INVN) * b2c;
    }
}

// ---------------------------------------------------------------------------
// LayerNorm over last dim (512), biased variance, optional clip; optionally
// also emits a bf16 copy (next layer's MFMA A-operand). One WG (2 waves)/row.
// ---------------------------------------------------------------------------
__global__ __launch_bounds__(128) void layer_norm(
    const float* __restrict__ u, const float* __restrict__ gamma,
    const float* __restrict__ beta, float* __restrict__ out,
    unsigned short* __restrict__ out_bf, int doClip)
{
    const int r   = blockIdx.x;
    const int tid = threadIdx.x;
    const float4 x = *(const float4*)&u[(size_t)r * DD + tid * 4];

    float s = x.x + x.y + x.z + x.w;
#pragma unroll
    for (int off = 32; off > 0; off >>= 1) s += __shfl_xor(s, off);

    __shared__ float red[2];
    __shared__ float red2[2];
    const int wid = tid >> 6;
    if ((tid & 63) == 0) red[wid] = s;
    __syncthreads();
    const float mu = (red[0] + red[1]) * (1.0f / 512.0f);

    const float dx = x.x - mu, dy = x.y - mu, dz = x.z - mu, dw = x.w - mu;
    float q = dx * dx + dy * dy + dz * dz + dw * dw;
#pragma unroll
    for (int off = 32; off > 0; off >>= 1) q += __shfl_xor(q, off);
    if ((tid & 63) == 0) red2[wid] = q;
    __syncthreads();
    const float var = (red2[0] + red2[1]) * (1.0f / 512.0f);
    const float rs  = rsqrtf(var + EPSF);

    const float4 g  = *(const float4*)&gamma[tid * 4];
    const float4 bt = *(const float4*)&beta[tid * 4];
    float4 y;
    y.x = dx * rs * g.x + bt.x;
    y.y = dy * rs * g.y + bt.y;
    y.z = dz * rs * g.z + bt.z;
    y.w = dw * rs * g.w + bt.w;
    if (doClip) {
        y.x = fminf(fmaxf(y.x, -100.f), 100.f);
        y.y = fminf(fmaxf(y.y, -100.f), 100.f);
        y.z = fminf(fmaxf(y.z, -100.f), 100.f);
        y.w = fminf(fmaxf(y.w, -100.f), 100.f);
    }
    *(float4*)&out[(size_t)r * DD + tid * 4] = y;

    if (out_bf) {
        uint2 p;
        p.x = (unsigned int)f2bf(y.x) | ((unsigned int)f2bf(y.y) << 16);
        p.y = (unsigned int)f2bf(y.z) | ((unsigned int)f2bf(y.w) << 16);
        *(uint2*)&out_bf[(size_t)r * DD + tid * 4] = p;
    }
}

// ---------------------------------------------------------------------------
extern "C" void kernel_launch(void* const* d_in, const int* in_sizes, int n_in,
                              void* d_out, int out_size, void* d_ws, size_t ws_size,
                              hipStream_t stream)
{
    const float* h0    = (const float*)d_in[0];  // (4,96,512)
    const float* adj   = (const float*)d_in[1];  // (4,96,96)
    const float* W1a   = (const float*)d_in[2];  // (2,512,512)
    const float* W1b   = (const float*)d_in[3];  // (2,512,512)
    const float* b1    = (const float*)d_in[4];  // (2,512)
    const float* W2    = (const float*)d_in[5];  // (2,512,512)
    const float* b2    = (const float*)d_in[6];  // (2,512)
    const float* gamma = (const float*)d_in[7];  // (512)
    const float* beta  = (const float*)d_in[8];  // (512)
    float* out = (float*)d_out;                  // (4,96,512)

    // workspace carve (bytes, all 256B-aligned sizes):
    char* p = (char*)d_ws;
    unsigned short* WT  = (unsigned short*)p;  p += 6u * DD * DD * 2;   // 3.00 MB
    unsigned short* Hbf = (unsigned short*)p;  p += MROWS * DD * 2;     // 384 KB
    unsigned short* Sbf = (unsigned short*)p;  p += MROWS * DD * 2;     // 384 KB
    float* A   = (float*)p;  p += MROWS * DD * 4;                       // 768 KB (a'; reused as U)
    float* Bb  = (float*)p;  p += MROWS * DD * 4;                       // 768 KB
    float* H1  = (float*)p;  p += MROWS * DD * 4;                       // 768 KB
    float* CNT = (float*)p;                                             // 1.5 KB

    // transpose+convert 6 weight matrices -> bf16 [n][k]; convert h0 -> bf16
    convert_w<<<dim3(16, 16, 7), dim3(32, 8), 0, stream>>>(W1a, W1b, W2, h0, WT, Hbf);

    for (int l = 0; l < 2; ++l) {
        const unsigned short* waT = WT + (size_t)(l * 3 + 0) * DD * DD;
        const unsigned short* wbT = WT + (size_t)(l * 3 + 1) * DD * DD;
        const unsigned short* w2T = WT + (size_t)(l * 3 + 2) * DD * DD;
        const float* bb1 = b1 + (size_t)l * DD;
        const float* bb2 = b2 + (size_t)l * DD;
        const float* hin = (l == 0) ? h0 : H1;
        float* hout = (l == 0) ? H1 : out;
        unsigned short* hbf_out = (l == 0) ? Hbf : nullptr;  // Hbf consumed by this
                                                             // layer's gemm_ab already

        gemm_ab<<<dim3(6, 32, 2), 256, 0, stream>>>(Hbf, waT, wbT, bb1, A, Bb);
        relusum<<<dim3(4, 24, 8), 64, 0, stream>>>(A, Bb, adj, Sbf, CNT);
        gemm_msg<<<dim3(6, 32), 256, 0, stream>>>(Sbf, w2T, bb2, CNT, hin, A /*=U*/);
        layer_norm<<<dim3(384), 128, 0, stream>>>(A /*=U*/, gamma, beta, hout,
                                                  hbf_out, l == 1);
    }
}